// Round 12
// baseline (207.123 us; speedup 1.0000x reference)
//
#include <hip/hip_runtime.h>

typedef short bf16x8 __attribute__((ext_vector_type(8)));
typedef short bf16x4 __attribute__((ext_vector_type(4)));
typedef float f32x4 __attribute__((ext_vector_type(4)));
typedef unsigned short ushort8 __attribute__((ext_vector_type(8)));
typedef unsigned short ushort4v __attribute__((ext_vector_type(4)));
typedef unsigned int uint4v __attribute__((ext_vector_type(4)));
typedef float float4v __attribute__((ext_vector_type(4)));

#define LOG2E 1.4426950408889634f
#define MASKED_VAL -14426.950408889634f /* -10000 * log2(e) */

__device__ __forceinline__ unsigned short f2bf(float f) {
  unsigned u = __builtin_bit_cast(unsigned, f);
  u = u + 0x7fffu + ((u >> 16) & 1u);
  return (unsigned short)(u >> 16);
}

// hardware packed f32->bf16 (RNE)
__device__ __forceinline__ unsigned pk2(float a, float b) {
  unsigned r;
  asm("v_cvt_pk_bf16_f32 %0, %1, %2" : "=v"(r) : "v"(a), "v"(b));
  return r;
}

// guaranteed single-instruction exp2
__device__ __forceinline__ float exp2a(float x) {
  float r;
  asm("v_exp_f32 %0, %1" : "=v"(r) : "v"(x));
  return r;
}

__device__ __forceinline__ void gload16(const void* g, void* l) {
  __builtin_amdgcn_global_load_lds(
      (const __attribute__((address_space(1))) unsigned int*)g,
      (__attribute__((address_space(3))) unsigned int*)l, 16, 0, 0);
}

// ---------------- W [K][N] fp32 -> Wt [N][K] bf16, all 4 weights fused ----------------
__global__ __launch_bounds__(256) void transpose_w4(const float* __restrict__ W0,
                                                    const float* __restrict__ W1,
                                                    const float* __restrict__ W2,
                                                    const float* __restrict__ W3,
                                                    unsigned short* __restrict__ Wt) {
  __shared__ float tile[32][33];
  const int z = blockIdx.z;
  const float* W = (z == 0) ? W0 : (z == 1) ? W1 : (z == 2) ? W2 : W3;
  unsigned short* o = Wt + (size_t)z * (1 << 20);
  int bx = blockIdx.x * 32;
  int by = blockIdx.y * 32;
  int tx = threadIdx.x & 31;
  int ty = threadIdx.x >> 5;
#pragma unroll
  for (int j = 0; j < 32; j += 8)
    tile[ty + j][tx] = W[(size_t)(by + ty + j) * 1024 + bx + tx];
  __syncthreads();
#pragma unroll
  for (int j = 0; j < 32; j += 8)
    o[(size_t)(bx + ty + j) * 1024 + by + tx] = f2bf(tile[tx][ty + j]);
}

// ---------------- Fused Q/K/V projection GEMM (128x256 tile, dbuf) ----------------
// grid = 768: logical = (g&7)*96 + (g>>3) (bijective XCD-chunked); chunk =
// logical/256 picks {srcQ,srcK,srcV}; bm = (logical%256)>>2, bn = logical&3.
// 4 waves (2x2), wave tile 64x128: a[4]+b[8] -> 32 MFMA (6B LDS/MFMA vs 8B at
// 64x64 — LDS-BW-bound fix). A fp32 reg-staged with fused cvt; V writes V^T.
__global__ __launch_bounds__(256, 2) void gemm_qkv(
    const float* __restrict__ srcQ, const float* __restrict__ srcK,
    const float* __restrict__ srcV, const unsigned short* __restrict__ Wt,
    const float* __restrict__ bq, const float* __restrict__ bk,
    const float* __restrict__ bv, unsigned short* __restrict__ Qb,
    unsigned short* __restrict__ Kb, unsigned short* __restrict__ Vt) {
  __shared__ __align__(16) unsigned short As[2][128 * 32];  // 16 KB
  __shared__ __align__(16) unsigned short Bs[2][256 * 32];  // 32 KB
  const int K = 1024, N = 1024;
  const int logical = (blockIdx.x & 7) * 96 + (blockIdx.x >> 3);
  const int chunk = logical >> 8;
  const int inner = logical & 255;
  const int bm = inner >> 2;
  const int bn = inner & 3;
  const float* Af = (chunk == 0) ? srcQ : (chunk == 1) ? srcK : srcV;
  const unsigned short* Bt = Wt + (size_t)chunk * (1 << 20);
  const float* bias = (chunk == 0) ? bq : (chunk == 1) ? bk : bv;
  const float scale = (chunk == 0) ? LOG2E : 1.0f;
  const int t = threadIdx.x;
  const int lane = t & 63, wid = t >> 6;
  const int wr = wid >> 1, wc = wid & 1;
  const int lr = lane & 15, lg = lane >> 4;
  f32x4 acc[4][8] = {};
  const size_t baseA = (size_t)(bm * 128) * K;
  const size_t baseB = (size_t)(bn * 256) * K;
  // A staging: 512 chunks (128 rows x 4), 2 per thread
  const int cA0 = t, cA1 = t + 256;
  const size_t a0off = baseA + (size_t)(cA0 >> 2) * K + (cA0 & 3) * 8;
  const size_t a1off = baseA + (size_t)(cA1 >> 2) * K + (cA1 & 3) * 8;
  // B staging: 1024 chunks (256 rows x 4), 4 per thread
  size_t boff[4];
#pragma unroll
  for (int i = 0; i < 4; ++i) {
    int ci = t + 256 * i;
    boff[i] = baseB + (size_t)(ci >> 2) * K + (ci & 3) * 8;
  }

  // prologue: stage tile 0
  {
    float4v f0 = *(const float4v*)&Af[a0off];
    float4v f1 = *(const float4v*)&Af[a0off + 4];
    float4v f2 = *(const float4v*)&Af[a1off];
    float4v f3 = *(const float4v*)&Af[a1off + 4];
#pragma unroll
    for (int i = 0; i < 4; ++i) gload16(&Bt[boff[i]], &Bs[0][(t + 256 * i) * 8]);
    uint4v w0, w1;
    w0[0] = pk2(f0[0], f0[1]); w0[1] = pk2(f0[2], f0[3]);
    w0[2] = pk2(f1[0], f1[1]); w0[3] = pk2(f1[2], f1[3]);
    w1[0] = pk2(f2[0], f2[1]); w1[1] = pk2(f2[2], f2[3]);
    w1[2] = pk2(f3[0], f3[1]); w1[3] = pk2(f3[2], f3[3]);
    *(uint4v*)&As[0][cA0 * 8] = w0;
    *(uint4v*)&As[0][cA1 * 8] = w1;
  }
  __syncthreads();

  int cur = 0;
  for (int ks = 0; ks < K; ks += 32) {
    const int nxt = cur ^ 1;
    const bool more = (ks + 32) < K;
    float4v f0, f1, f2, f3;
    if (more) {
      f0 = *(const float4v*)&Af[a0off + ks + 32];
      f1 = *(const float4v*)&Af[a0off + ks + 36];
      f2 = *(const float4v*)&Af[a1off + ks + 32];
      f3 = *(const float4v*)&Af[a1off + ks + 36];
#pragma unroll
      for (int i = 0; i < 4; ++i)
        gload16(&Bt[boff[i] + ks + 32], &Bs[nxt][(t + 256 * i) * 8]);
    }
    bf16x8 a[4], b[8];
#pragma unroll
    for (int m = 0; m < 4; ++m)
      a[m] = *(const bf16x8*)&As[cur][(wr * 64 + 16 * m + lr) * 32 + lg * 8];
#pragma unroll
    for (int n = 0; n < 8; ++n)
      b[n] = *(const bf16x8*)&Bs[cur][(wc * 128 + 16 * n + lr) * 32 + lg * 8];
#pragma unroll
    for (int m = 0; m < 4; ++m)
#pragma unroll
      for (int n = 0; n < 8; ++n)
        acc[m][n] = __builtin_amdgcn_mfma_f32_16x16x32_bf16(a[m], b[n], acc[m][n], 0, 0, 0);
    if (more) {
      uint4v w0, w1;
      w0[0] = pk2(f0[0], f0[1]); w0[1] = pk2(f0[2], f0[3]);
      w0[2] = pk2(f1[0], f1[1]); w0[3] = pk2(f1[2], f1[3]);
      w1[0] = pk2(f2[0], f2[1]); w1[1] = pk2(f2[2], f2[3]);
      w1[2] = pk2(f3[0], f3[1]); w1[3] = pk2(f3[2], f3[3]);
      *(uint4v*)&As[nxt][cA0 * 8] = w0;
      *(uint4v*)&As[nxt][cA1 * 8] = w1;
    }
    __syncthreads();
    cur = nxt;
  }
  const int rowb = bm * 128 + wr * 64;
  const int colb = bn * 256 + wc * 128;
  if (chunk == 2) {
    const int bidx = rowb >> 11;
    const int srow = rowb & 2047;
#pragma unroll
    for (int n = 0; n < 8; ++n) {
      int col = colb + 16 * n + lr;
      float bv_ = bias[col];
#pragma unroll
      for (int m = 0; m < 4; ++m) {
        int s0 = srow + 16 * m + 4 * lg;
        ushort4v u;
#pragma unroll
        for (int r = 0; r < 4; ++r) u[r] = f2bf(acc[m][n][r] + bv_);
        *(ushort4v*)&Vt[((size_t)(bidx * 1024 + col)) * 2048 + s0] = u;
      }
    }
  } else {
    unsigned short* C = (chunk == 0) ? Qb : Kb;
#pragma unroll
    for (int n = 0; n < 8; ++n) {
      int col = colb + 16 * n + lr;
      float bv_ = bias[col];
#pragma unroll
      for (int m = 0; m < 4; ++m) {
        int row0 = rowb + 16 * m + 4 * lg;
#pragma unroll
        for (int r = 0; r < 4; ++r)
          C[(size_t)(row0 + r) * N + col] = f2bf((acc[m][n][r] + bv_) * scale);
      }
    }
  }
}

// ---------------- Wo GEMM: out[M,N] = ctx[M,K](bf16) * Wt[N,K]^T + bias (fp32 out) ----------------
// 128x256 tile, dbuf, grid = 256, bijective XCD swizzle.
__global__ __launch_bounds__(256, 2) void gemm_out(const unsigned short* __restrict__ A,
                                                   const unsigned short* __restrict__ Bt,
                                                   const float* __restrict__ bias,
                                                   float* __restrict__ C) {
  __shared__ __align__(16) unsigned short As[2][128 * 32];
  __shared__ __align__(16) unsigned short Bs[2][256 * 32];
  const int K = 1024, N = 1024;
  const int logical = (blockIdx.x & 7) * 32 + (blockIdx.x >> 3);
  const int bm = logical >> 2;
  const int bn = logical & 3;
  const int t = threadIdx.x;
  const int lane = t & 63, wid = t >> 6;
  const int wr = wid >> 1, wc = wid & 1;
  const int lr = lane & 15, lg = lane >> 4;
  f32x4 acc[4][8] = {};
  const size_t baseA = (size_t)(bm * 128) * K;
  const size_t baseB = (size_t)(bn * 256) * K;
  const int cA0 = t, cA1 = t + 256;
  const size_t a0off = baseA + (size_t)(cA0 >> 2) * K + (cA0 & 3) * 8;
  const size_t a1off = baseA + (size_t)(cA1 >> 2) * K + (cA1 & 3) * 8;
  size_t boff[4];
#pragma unroll
  for (int i = 0; i < 4; ++i) {
    int ci = t + 256 * i;
    boff[i] = baseB + (size_t)(ci >> 2) * K + (ci & 3) * 8;
  }

  gload16(&A[a0off], &As[0][cA0 * 8]);
  gload16(&A[a1off], &As[0][cA1 * 8]);
#pragma unroll
  for (int i = 0; i < 4; ++i) gload16(&Bt[boff[i]], &Bs[0][(t + 256 * i) * 8]);
  __syncthreads();

  int cur = 0;
  for (int ks = 0; ks < K; ks += 32) {
    const int nxt = cur ^ 1;
    if (ks + 32 < K) {
      gload16(&A[a0off + ks + 32], &As[nxt][cA0 * 8]);
      gload16(&A[a1off + ks + 32], &As[nxt][cA1 * 8]);
#pragma unroll
      for (int i = 0; i < 4; ++i)
        gload16(&Bt[boff[i] + ks + 32], &Bs[nxt][(t + 256 * i) * 8]);
    }
    bf16x8 a[4], b[8];
#pragma unroll
    for (int m = 0; m < 4; ++m)
      a[m] = *(const bf16x8*)&As[cur][(wr * 64 + 16 * m + lr) * 32 + lg * 8];
#pragma unroll
    for (int n = 0; n < 8; ++n)
      b[n] = *(const bf16x8*)&Bs[cur][(wc * 128 + 16 * n + lr) * 32 + lg * 8];
#pragma unroll
    for (int m = 0; m < 4; ++m)
#pragma unroll
      for (int n = 0; n < 8; ++n)
        acc[m][n] = __builtin_amdgcn_mfma_f32_16x16x32_bf16(a[m], b[n], acc[m][n], 0, 0, 0);
    __syncthreads();
    cur = nxt;
  }
  const int rowb = bm * 128 + wr * 64;
  const int colb = bn * 256 + wc * 128;
#pragma unroll
  for (int n = 0; n < 8; ++n) {
    int col = colb + 16 * n + lr;
    float bv = bias[col];
#pragma unroll
    for (int m = 0; m < 4; ++m) {
      int row0 = rowb + 16 * m + 4 * lg;
#pragma unroll
      for (int r = 0; r < 4; ++r)
        C[(size_t)(row0 + r) * N + col] = acc[m][n][r] + bv;
    }
  }
}

// ---------------- Flash attention (swapped-operand, direct-exp2 softmax) ----------------
// grid = 1024, XCD-swizzled. 4 waves x 32 q-rows, KVBLK=64, dbuf.
// No max tracking: scores are bounded (|S*log2e| ~ 13 << 127), so P = exp2(S)
// directly; l via ones-MFMA; O/l normalizes at the end. Masked -> exp2(-14427)=0.
__global__ __launch_bounds__(256, 4) void attn_kernel(
    const unsigned short* __restrict__ Q, const unsigned short* __restrict__ K,
    const unsigned short* __restrict__ V, const int* __restrict__ mask,
    unsigned short* __restrict__ ctx) {
  __shared__ __align__(16) unsigned short pool[16384];  // 32 KB
  __shared__ int s_any[4];
  unsigned short* Kbuf0 = pool;
  unsigned short* Kbuf1 = pool + 4096;
  unsigned short* Vbuf0 = pool + 8192;
  unsigned short* Vbuf1 = pool + 12288;
  const int g = blockIdx.x;
  const int bid = (g & 7) * 128 + (g >> 3);  // XCD-contiguous logical id
  const int qb = bid & 15, h = (bid >> 4) & 15, b = bid >> 8;
  const int t = threadIdx.x;
  const int lane = t & 63, wid = t >> 6;
  const int lr = lane & 15, lg = lane >> 4;
  const size_t rowQ0 = (size_t)(b * 2048 + qb * 128);
  const int hcol = h * 64;
  const size_t vrow0 = (size_t)((b * 16 + h) * 64) * 2048;

  size_t ksrc[2], vsrc[2];
  int ldso[2];
#pragma unroll
  for (int i = 0; i < 2; ++i) {
    int ci = t + 256 * i;  // 0..511
    int row = ci >> 3, pos = ci & 7;
    ksrc[i] = (size_t)(b * 2048 + row) * 1024 + hcol + ((pos ^ (row & 7)) << 3);
    vsrc[i] = vrow0 + (size_t)row * 2048 + ((pos ^ ((row >> 1) & 7)) << 3);
    ldso[i] = ci * 8;
  }
  // stage Q tile [128 q][64 d] into pool (K region, pre-loop reuse)
#pragma unroll
  for (int i = 0; i < 4; ++i) {
    int ci = t + 256 * i;
    int row = ci >> 3, pos = ci & 7;
    gload16(&Q[(rowQ0 + row) * 1024 + hcol + ((pos ^ (row & 7)) << 3)], &pool[ci * 8]);
  }
  // block-wide mask scan
  int bad = 0;
  const int* mb = mask + b * 2048;
#pragma unroll
  for (int i = 0; i < 2; ++i) {
    int4 mv = *(const int4*)&mb[t * 8 + i * 4];
    bad |= (mv.x == 0) | (mv.y == 0) | (mv.z == 0) | (mv.w == 0);
  }
  unsigned long long bb = __ballot(bad);
  if (lane == 0) s_any[wid] = (bb != 0ULL);
  __syncthreads();
  bf16x8 aq[2][2];
#pragma unroll
  for (int m = 0; m < 2; ++m)
#pragma unroll
    for (int kd = 0; kd < 2; ++kd) {
      int row = wid * 32 + 16 * m + lr;
      int ch = (4 * kd + lg) ^ (lr & 7);
      aq[m][kd] = *(const bf16x8*)&pool[row * 64 + ch * 8];
    }
  const bool anymask = (s_any[0] | s_any[1] | s_any[2] | s_any[3]) != 0;
  __syncthreads();
#pragma unroll
  for (int i = 0; i < 2; ++i) gload16(&K[ksrc[i]], &Kbuf0[ldso[i]]);
#pragma unroll
  for (int i = 0; i < 2; ++i) gload16(&V[vsrc[i]], &Vbuf0[ldso[i]]);
  __syncthreads();

  f32x4 o[2][4] = {};
  f32x4 ol[2] = {};
  const short oneb = 0x3F80;
  const bf16x8 ones8 = {oneb, oneb, oneb, oneb, oneb, oneb, oneb, oneb};
  const f32x4 zero4 = {0.f, 0.f, 0.f, 0.f};
  const int ch0 = (lg ^ (lr & 7)) * 8;
  const int ch1 = ((4 + lg) ^ (lr & 7)) * 8;
  const int sw = lr >> 1;

  for (int kb = 0; kb < 32; ++kb) {
    const int bi = kb & 1;
    const unsigned short* Kb_ = bi ? Kbuf1 : Kbuf0;
    const unsigned short* Vb_ = bi ? Vbuf1 : Vbuf0;
    unsigned short* Kn_ = bi ? Kbuf0 : Kbuf1;
    unsigned short* Vn_ = bi ? Vbuf0 : Vbuf1;
    if (kb + 1 < 32) {
      const size_t ko = (size_t)(kb + 1) * 64 * 1024;
      const size_t vo = (size_t)(kb + 1) * 64;
#pragma unroll
      for (int i = 0; i < 2; ++i) gload16(&K[ksrc[i] + ko], &Kn_[ldso[i]]);
#pragma unroll
      for (int i = 0; i < 2; ++i) gload16(&V[vsrc[i] + vo], &Vn_[ldso[i]]);
    }
    // ---- S^T = K Q^T ----
    f32x4 s[2][4];
    __builtin_amdgcn_s_setprio(1);
#pragma unroll
    for (int n = 0; n < 4; ++n) {
      bf16x8 k0 = *(const bf16x8*)&Kb_[(16 * n + lr) * 64 + ch0];
      bf16x8 k1 = *(const bf16x8*)&Kb_[(16 * n + lr) * 64 + ch1];
      f32x4 t0 = __builtin_amdgcn_mfma_f32_16x16x32_bf16(k0, aq[0][0], zero4, 0, 0, 0);
      s[0][n] = __builtin_amdgcn_mfma_f32_16x16x32_bf16(k1, aq[0][1], t0, 0, 0, 0);
      f32x4 t1 = __builtin_amdgcn_mfma_f32_16x16x32_bf16(k0, aq[1][0], zero4, 0, 0, 0);
      s[1][n] = __builtin_amdgcn_mfma_f32_16x16x32_bf16(k1, aq[1][1], t1, 0, 0, 0);
    }
    __builtin_amdgcn_s_setprio(0);
    if (anymask) {
      const int* mrow = mb + kb * 64;
#pragma unroll
      for (int n = 0; n < 4; ++n) {
        int4 mv = *(const int4*)&mrow[16 * n + 4 * lg];
        int mm[4] = {mv.x, mv.y, mv.z, mv.w};
#pragma unroll
        for (int r = 0; r < 4; ++r)
          if (mm[r] == 0) { s[0][n][r] = MASKED_VAL; s[1][n][r] = MASKED_VAL; }
      }
    }
    // ---- direct exp2 (no max tracking: scores bounded far below overflow) ----
#pragma unroll
    for (int m = 0; m < 2; ++m)
#pragma unroll
      for (int n = 0; n < 4; ++n)
#pragma unroll
        for (int r = 0; r < 4; ++r) s[m][n][r] = exp2a(s[m][n][r]);
    // ---- O^T += V^T P^T (permuted k-slots); l via ones-MFMA ----
#pragma unroll
    for (int kk = 0; kk < 2; ++kk) {
      bf16x8 pf[2];
#pragma unroll
      for (int m = 0; m < 2; ++m) {
        uint4v u;
        u[0] = pk2(s[m][2 * kk][0], s[m][2 * kk][1]);
        u[1] = pk2(s[m][2 * kk][2], s[m][2 * kk][3]);
        u[2] = pk2(s[m][2 * kk + 1][0], s[m][2 * kk + 1][1]);
        u[3] = pk2(s[m][2 * kk + 1][2], s[m][2 * kk + 1][3]);
        pf[m] = __builtin_bit_cast(bf16x8, u);
      }
      __builtin_amdgcn_s_setprio(1);
      ol[0] = __builtin_amdgcn_mfma_f32_16x16x32_bf16(ones8, pf[0], ol[0], 0, 0, 0);
      ol[1] = __builtin_amdgcn_mfma_f32_16x16x32_bf16(ones8, pf[1], ol[1], 0, 0, 0);
      const int p0 = (4 * kk + (lg >> 1)) ^ sw;
      const int base0 = lr * 64 + p0 * 8 + (lg & 1) * 4;
      const int base1 = lr * 64 + (p0 ^ 2) * 8 + (lg & 1) * 4;
#pragma unroll
      for (int dn = 0; dn < 4; ++dn) {
        bf16x4 v0 = *(const bf16x4*)&Vb_[base0 + dn * 1024];
        bf16x4 v1 = *(const bf16x4*)&Vb_[base1 + dn * 1024];
        bf16x8 vb = __builtin_shufflevector(v0, v1, 0, 1, 2, 3, 4, 5, 6, 7);
#pragma unroll
        for (int m = 0; m < 2; ++m)
          o[m][dn] = __builtin_amdgcn_mfma_f32_16x16x32_bf16(vb, pf[m], o[m][dn], 0, 0, 0);
      }
      __builtin_amdgcn_s_setprio(0);
    }
    __syncthreads();
  }
  // ---- epilogue ----
#pragma unroll
  for (int m = 0; m < 2; ++m) {
    float inv = 1.f / ol[m][0];
    size_t q = rowQ0 + wid * 32 + 16 * m + lr;
#pragma unroll
    for (int dn = 0; dn < 4; ++dn) {
      ushort4v u;
#pragma unroll
      for (int r = 0; r < 4; ++r) u[r] = f2bf(o[m][dn][r] * inv);
      *(ushort4v*)&ctx[q * 1024 + hcol + 16 * dn + 4 * lg] = u;
    }
  }
}

extern "C" void kernel_launch(void* const* d_in, const int* in_sizes, int n_in,
                              void* d_out, int out_size, void* d_ws, size_t ws_size,
                              hipStream_t stream) {
  const float* srcQ = (const float*)d_in[0];
  const float* srcK = (const float*)d_in[1];
  const float* srcV = (const float*)d_in[2];
  const int*   mask = (const int*)d_in[3];
  const float* Wq = (const float*)d_in[4];
  const float* bq = (const float*)d_in[5];
  const float* Wk = (const float*)d_in[6];
  const float* bk = (const float*)d_in[7];
  const float* Wv = (const float*)d_in[8];
  const float* bv = (const float*)d_in[9];
  const float* Wo = (const float*)d_in[10];
  const float* bo = (const float*)d_in[11];
  float* out = (float*)d_out;

  char* ws = (char*)d_ws;
  unsigned short* ctx = (unsigned short*)(ws);                       // 16 MiB
  unsigned short* Qb  = (unsigned short*)(ws + (size_t)(16 << 20));
  unsigned short* Kb  = (unsigned short*)(ws + (size_t)(32 << 20));
  unsigned short* Vt  = (unsigned short*)(ws + (size_t)(48 << 20));  // V^T from V-GEMM
  unsigned short* Wt  = (unsigned short*)(ws + (size_t)(64 << 20));  // 4 x 2 MiB

  transpose_w4<<<dim3(32, 32, 4), 256, 0, stream>>>(Wq, Wk, Wv, Wo, Wt);

  gemm_qkv<<<768, 256, 0, stream>>>(srcQ, srcK, srcV, Wt, bq, bk, bv, Qb, Kb, Vt);

  attn_kernel<<<1024, 256, 0, stream>>>(Qb, Kb, Vt, mask, ctx);

  gemm_out<<<256, 256, 0, stream>>>(ctx, Wt + 3 * (1 << 20), bo, out);
}

// Round 13
// 180.862 us; speedup vs baseline: 1.1452x; 1.1452x over previous
//
#include <hip/hip_runtime.h>

typedef short bf16x8 __attribute__((ext_vector_type(8)));
typedef short bf16x4 __attribute__((ext_vector_type(4)));
typedef float f32x4 __attribute__((ext_vector_type(4)));
typedef unsigned short ushort8 __attribute__((ext_vector_type(8)));
typedef unsigned short ushort4v __attribute__((ext_vector_type(4)));
typedef unsigned int uint4v __attribute__((ext_vector_type(4)));
typedef float float4v __attribute__((ext_vector_type(4)));

#define LOG2E 1.4426950408889634f
#define MASKED_VAL -14426.950408889634f /* -10000 * log2(e) */

__device__ __forceinline__ unsigned short f2bf(float f) {
  unsigned u = __builtin_bit_cast(unsigned, f);
  u = u + 0x7fffu + ((u >> 16) & 1u);
  return (unsigned short)(u >> 16);
}

__device__ __forceinline__ unsigned pk2(float a, float b) {
  unsigned r;
  asm("v_cvt_pk_bf16_f32 %0, %1, %2" : "=v"(r) : "v"(a), "v"(b));
  return r;
}

__device__ __forceinline__ float exp2a(float x) {
  float r;
  asm("v_exp_f32 %0, %1" : "=v"(r) : "v"(x));
  return r;
}

__device__ __forceinline__ void gload16(const void* g, void* l) {
  __builtin_amdgcn_global_load_lds(
      (const __attribute__((address_space(1))) unsigned int*)g,
      (__attribute__((address_space(3))) unsigned int*)l, 16, 0, 0);
}

// ---------------- W [K][N] fp32 -> Wt [N][K] bf16, all 4 weights fused ----------------
__global__ __launch_bounds__(256) void transpose_w4(const float* __restrict__ W0,
                                                    const float* __restrict__ W1,
                                                    const float* __restrict__ W2,
                                                    const float* __restrict__ W3,
                                                    unsigned short* __restrict__ Wt) {
  __shared__ float tile[32][33];
  const int z = blockIdx.z;
  const float* W = (z == 0) ? W0 : (z == 1) ? W1 : (z == 2) ? W2 : W3;
  unsigned short* o = Wt + (size_t)z * (1 << 20);
  int bx = blockIdx.x * 32;
  int by = blockIdx.y * 32;
  int tx = threadIdx.x & 31;
  int ty = threadIdx.x >> 5;
#pragma unroll
  for (int j = 0; j < 32; j += 8)
    tile[ty + j][tx] = W[(size_t)(by + ty + j) * 1024 + bx + tx];
  __syncthreads();
#pragma unroll
  for (int j = 0; j < 32; j += 8)
    o[(size_t)(bx + ty + j) * 1024 + by + tx] = f2bf(tile[tx][ty + j]);
}

// ---------------- Fused Q/K/V projection GEMM (128x128, 3-buffer, no-drain barriers) ----------------
// Prefetch distance 2: during tile t stage tile t+2 (B via gload_lds, A fp32 via
// regs). A(t+1) cvt+ds_write happens inside tile t -> the compiler's wait for the
// A regs retires B(t+1) too, so the tile boundary needs only lgkmcnt(0) + raw
// s_barrier (never a vmcnt(0) drain).
__global__ __launch_bounds__(256, 3) void gemm_qkv(
    const float* __restrict__ srcQ, const float* __restrict__ srcK,
    const float* __restrict__ srcV, const unsigned short* __restrict__ Wt,
    const float* __restrict__ bq, const float* __restrict__ bk,
    const float* __restrict__ bv, unsigned short* __restrict__ Qb,
    unsigned short* __restrict__ Kb, unsigned short* __restrict__ Vt) {
  __shared__ __align__(16) unsigned short As[3][128 * 32];  // 24 KB
  __shared__ __align__(16) unsigned short Bs[3][128 * 32];  // 24 KB
  const int K = 1024, N = 1024;
  const int chunk = blockIdx.x >> 9;
  const int inner = blockIdx.x & 511;
  const int x = inner & 7, i = inner >> 3;
  const int bm = (x << 3) + (i >> 3);
  const int bn = i & 7;
  const float* Af = (chunk == 0) ? srcQ : (chunk == 1) ? srcK : srcV;
  const unsigned short* Bt = Wt + (size_t)chunk * (1 << 20);
  const float* bias = (chunk == 0) ? bq : (chunk == 1) ? bk : bv;
  const float scale = (chunk == 0) ? LOG2E : 1.0f;
  const int t = threadIdx.x;
  const int lane = t & 63, wid = t >> 6;
  const int wr = wid >> 1, wc = wid & 1;
  const int lr = lane & 15, lg = lane >> 4;
  f32x4 acc[4][4] = {};
  const size_t baseA = (size_t)(bm * 128) * K;
  const size_t baseB = (size_t)(bn * 128) * K;
  const int c0 = t, c1 = t + 256;
  const size_t a0off = baseA + (size_t)(c0 >> 2) * K + (c0 & 3) * 8;
  const size_t a1off = baseA + (size_t)(c1 >> 2) * K + (c1 & 3) * 8;
  const size_t b0off = baseB + (size_t)(c0 >> 2) * K + (c0 & 3) * 8;
  const size_t b1off = baseB + (size_t)(c1 >> 2) * K + (c1 & 3) * 8;

  unsigned short* pA0 = &As[0][0];
  unsigned short* pA1 = &As[1][0];
  unsigned short* pA2 = &As[2][0];
  unsigned short* pB0 = &Bs[0][0];
  unsigned short* pB1 = &Bs[1][0];
  unsigned short* pB2 = &Bs[2][0];
  float4v fE[4], fO[4];

  auto loadA = [&](float4v* f, int ks) {
    f[0] = *(const float4v*)&Af[a0off + ks];
    f[1] = *(const float4v*)&Af[a0off + ks + 4];
    f[2] = *(const float4v*)&Af[a1off + ks];
    f[3] = *(const float4v*)&Af[a1off + ks + 4];
  };
  auto writeA = [&](const float4v* f, unsigned short* dst) {
    uint4v w0, w1;
    w0[0] = pk2(f[0][0], f[0][1]); w0[1] = pk2(f[0][2], f[0][3]);
    w0[2] = pk2(f[1][0], f[1][1]); w0[3] = pk2(f[1][2], f[1][3]);
    w1[0] = pk2(f[2][0], f[2][1]); w1[1] = pk2(f[2][2], f[2][3]);
    w1[2] = pk2(f[3][0], f[3][1]); w1[3] = pk2(f[3][2], f[3][3]);
    *(uint4v*)&dst[c0 * 8] = w0;
    *(uint4v*)&dst[c1 * 8] = w1;
  };
  auto compute = [&]() {
    bf16x8 a[4], b[4];
#pragma unroll
    for (int m = 0; m < 4; ++m)
      a[m] = *(const bf16x8*)&pA0[(wr * 64 + 16 * m + lr) * 32 + lg * 8];
#pragma unroll
    for (int n = 0; n < 4; ++n)
      b[n] = *(const bf16x8*)&pB0[(wc * 64 + 16 * n + lr) * 32 + lg * 8];
    __builtin_amdgcn_s_setprio(1);
#pragma unroll
    for (int m = 0; m < 4; ++m)
#pragma unroll
      for (int n = 0; n < 4; ++n)
        acc[m][n] = __builtin_amdgcn_mfma_f32_16x16x32_bf16(a[m], b[n], acc[m][n], 0, 0, 0);
    __builtin_amdgcn_s_setprio(0);
  };
  auto rotate = [&]() {
    unsigned short* ta = pA0; pA0 = pA1; pA1 = pA2; pA2 = ta;
    unsigned short* tb = pB0; pB0 = pB1; pB1 = pB2; pB2 = tb;
  };

  // ---- prologue: stage tiles 0,1; write A(0); enter with A(1) in fO ----
  gload16(&Bt[b0off], &pB0[c0 * 8]);
  gload16(&Bt[b1off], &pB0[c1 * 8]);
  loadA(fE, 0);
  gload16(&Bt[b0off + 32], &pB1[c0 * 8]);
  gload16(&Bt[b1off + 32], &pB1[c1 * 8]);
  loadA(fO, 32);
  writeA(fE, pA0);  // compiler vm-wait here also retires B(0)
  asm volatile("s_waitcnt lgkmcnt(0)" ::: "memory");
  __builtin_amdgcn_s_barrier();

  for (int it = 0; it < 16; ++it) {
    const int ks0 = 64 * it;
    // ---- even tile t0 = 2it ----
    if (it < 15) {
      gload16(&Bt[b0off + ks0 + 64], &pB2[c0 * 8]);
      gload16(&Bt[b1off + ks0 + 64], &pB2[c1 * 8]);
      loadA(fE, ks0 + 64);  // A(t0+2)
    }
    compute();
    writeA(fO, pA1);  // A(t0+1); compiler vm-wait retires B(t0+1)
    asm volatile("s_waitcnt lgkmcnt(0)" ::: "memory");
    __builtin_amdgcn_sched_barrier(0);
    __builtin_amdgcn_s_barrier();
    rotate();
    // ---- odd tile t1 = 2it+1 ----
    if (it < 15) {
      gload16(&Bt[b0off + ks0 + 96], &pB2[c0 * 8]);
      gload16(&Bt[b1off + ks0 + 96], &pB2[c1 * 8]);
      loadA(fO, ks0 + 96);  // A(t1+2)
    }
    compute();
    if (it < 15) {
      writeA(fE, pA1);  // A(t1+1)
      asm volatile("s_waitcnt lgkmcnt(0)" ::: "memory");
      __builtin_amdgcn_sched_barrier(0);
      __builtin_amdgcn_s_barrier();
      rotate();
    }
  }

  const int rowb = bm * 128 + wr * 64;
  const int colb = bn * 128 + wc * 64;
  if (chunk == 2) {
    const int bidx = rowb >> 11;
    const int srow = rowb & 2047;
#pragma unroll
    for (int n = 0; n < 4; ++n) {
      int col = colb + 16 * n + lr;
      float bv_ = bias[col];
#pragma unroll
      for (int m = 0; m < 4; ++m) {
        int s0 = srow + 16 * m + 4 * lg;
        ushort4v u;
#pragma unroll
        for (int r = 0; r < 4; ++r) u[r] = f2bf(acc[m][n][r] + bv_);
        *(ushort4v*)&Vt[((size_t)(bidx * 1024 + col)) * 2048 + s0] = u;
      }
    }
  } else {
    unsigned short* C = (chunk == 0) ? Qb : Kb;
#pragma unroll
    for (int n = 0; n < 4; ++n) {
      int col = colb + 16 * n + lr;
      float bv_ = bias[col];
#pragma unroll
      for (int m = 0; m < 4; ++m) {
        int row0 = rowb + 16 * m + 4 * lg;
#pragma unroll
        for (int r = 0; r < 4; ++r)
          C[(size_t)(row0 + r) * N + col] = f2bf((acc[m][n][r] + bv_) * scale);
      }
    }
  }
}

// ---------------- Wo GEMM: out = ctx(bf16) * Wt^T + bias (fp32 out) ----------------
// 128x128, 3-buffer, counted vmcnt(4) boundaries (never drain to 0 in main loop).
__global__ __launch_bounds__(256, 3) void gemm_out(const unsigned short* __restrict__ A,
                                                   const unsigned short* __restrict__ Bt,
                                                   const float* __restrict__ bias,
                                                   float* __restrict__ C) {
  __shared__ __align__(16) unsigned short As[3][128 * 32];
  __shared__ __align__(16) unsigned short Bs[3][128 * 32];
  const int K = 1024, N = 1024;
  const int x = blockIdx.x & 7, i = blockIdx.x >> 3;
  const int bm = (x << 3) + (i >> 3);
  const int bn = i & 7;
  const int t = threadIdx.x;
  const int lane = t & 63, wid = t >> 6;
  const int wr = wid >> 1, wc = wid & 1;
  const int lr = lane & 15, lg = lane >> 4;
  f32x4 acc[4][4] = {};
  const size_t baseA = (size_t)(bm * 128) * K;
  const size_t baseB = (size_t)(bn * 128) * K;
  const int c0 = t, c1 = t + 256;
  const size_t a0off = baseA + (size_t)(c0 >> 2) * K + (c0 & 3) * 8;
  const size_t a1off = baseA + (size_t)(c1 >> 2) * K + (c1 & 3) * 8;
  const size_t b0off = baseB + (size_t)(c0 >> 2) * K + (c0 & 3) * 8;
  const size_t b1off = baseB + (size_t)(c1 >> 2) * K + (c1 & 3) * 8;

  unsigned short* pA0 = &As[0][0];
  unsigned short* pA1 = &As[1][0];
  unsigned short* pA2 = &As[2][0];
  unsigned short* pB0 = &Bs[0][0];
  unsigned short* pB1 = &Bs[1][0];
  unsigned short* pB2 = &Bs[2][0];

  auto issue = [&](int ks, unsigned short* dA, unsigned short* dB) {
    gload16(&A[a0off + ks], &dA[c0 * 8]);
    gload16(&A[a1off + ks], &dA[c1 * 8]);
    gload16(&Bt[b0off + ks], &dB[c0 * 8]);
    gload16(&Bt[b1off + ks], &dB[c1 * 8]);
  };
  auto rotate = [&]() {
    unsigned short* ta = pA0; pA0 = pA1; pA1 = pA2; pA2 = ta;
    unsigned short* tb = pB0; pB0 = pB1; pB1 = pB2; pB2 = tb;
  };

  issue(0, pA0, pB0);
  issue(32, pA1, pB1);
  asm volatile("s_waitcnt vmcnt(4)" ::: "memory");
  __builtin_amdgcn_sched_barrier(0);
  __builtin_amdgcn_s_barrier();

  for (int tt = 0; tt < 32; ++tt) {
    if (tt < 30) issue(32 * tt + 64, pA2, pB2);
    bf16x8 a[4], b[4];
#pragma unroll
    for (int m = 0; m < 4; ++m)
      a[m] = *(const bf16x8*)&pA0[(wr * 64 + 16 * m + lr) * 32 + lg * 8];
#pragma unroll
    for (int n = 0; n < 4; ++n)
      b[n] = *(const bf16x8*)&pB0[(wc * 64 + 16 * n + lr) * 32 + lg * 8];
    __builtin_amdgcn_s_setprio(1);
#pragma unroll
    for (int m = 0; m < 4; ++m)
#pragma unroll
      for (int n = 0; n < 4; ++n)
        acc[m][n] = __builtin_amdgcn_mfma_f32_16x16x32_bf16(a[m], b[n], acc[m][n], 0, 0, 0);
    __builtin_amdgcn_s_setprio(0);
    if (tt < 31) {
      if (tt < 30) {
        asm volatile("s_waitcnt vmcnt(4)" ::: "memory");
      } else {
        asm volatile("s_waitcnt vmcnt(0)" ::: "memory");
      }
      __builtin_amdgcn_sched_barrier(0);
      __builtin_amdgcn_s_barrier();
      rotate();
    }
  }

  const int rowb = bm * 128 + wr * 64;
  const int colb = bn * 128 + wc * 64;
#pragma unroll
  for (int n = 0; n < 4; ++n) {
    int col = colb + 16 * n + lr;
    float bv = bias[col];
#pragma unroll
    for (int m = 0; m < 4; ++m) {
      int row0 = rowb + 16 * m + 4 * lg;
#pragma unroll
      for (int r = 0; r < 4; ++r)
        C[(size_t)(row0 + r) * N + col] = acc[m][n][r] + bv;
    }
  }
}

// ---------------- Flash attention (swapped-operand, direct-exp2 softmax) ----------------
// grid = 1024, XCD-swizzled. 4 waves x 32 q-rows, KVBLK=64, dbuf.
__global__ __launch_bounds__(256, 4) void attn_kernel(
    const unsigned short* __restrict__ Q, const unsigned short* __restrict__ K,
    const unsigned short* __restrict__ V, const int* __restrict__ mask,
    unsigned short* __restrict__ ctx) {
  __shared__ __align__(16) unsigned short pool[16384];  // 32 KB
  __shared__ int s_any[4];
  unsigned short* Kbuf0 = pool;
  unsigned short* Kbuf1 = pool + 4096;
  unsigned short* Vbuf0 = pool + 8192;
  unsigned short* Vbuf1 = pool + 12288;
  const int g = blockIdx.x;
  const int bid = (g & 7) * 128 + (g >> 3);
  const int qb = bid & 15, h = (bid >> 4) & 15, b = bid >> 8;
  const int t = threadIdx.x;
  const int lane = t & 63, wid = t >> 6;
  const int lr = lane & 15, lg = lane >> 4;
  const size_t rowQ0 = (size_t)(b * 2048 + qb * 128);
  const int hcol = h * 64;
  const size_t vrow0 = (size_t)((b * 16 + h) * 64) * 2048;

  size_t ksrc[2], vsrc[2];
  int ldso[2];
#pragma unroll
  for (int i = 0; i < 2; ++i) {
    int ci = t + 256 * i;
    int row = ci >> 3, pos = ci & 7;
    ksrc[i] = (size_t)(b * 2048 + row) * 1024 + hcol + ((pos ^ (row & 7)) << 3);
    vsrc[i] = vrow0 + (size_t)row * 2048 + ((pos ^ ((row >> 1) & 7)) << 3);
    ldso[i] = ci * 8;
  }
#pragma unroll
  for (int i = 0; i < 4; ++i) {
    int ci = t + 256 * i;
    int row = ci >> 3, pos = ci & 7;
    gload16(&Q[(rowQ0 + row) * 1024 + hcol + ((pos ^ (row & 7)) << 3)], &pool[ci * 8]);
  }
  int bad = 0;
  const int* mb = mask + b * 2048;
#pragma unroll
  for (int i = 0; i < 2; ++i) {
    int4 mv = *(const int4*)&mb[t * 8 + i * 4];
    bad |= (mv.x == 0) | (mv.y == 0) | (mv.z == 0) | (mv.w == 0);
  }
  unsigned long long bb = __ballot(bad);
  if (lane == 0) s_any[wid] = (bb != 0ULL);
  __syncthreads();
  bf16x8 aq[2][2];
#pragma unroll
  for (int m = 0; m < 2; ++m)
#pragma unroll
    for (int kd = 0; kd < 2; ++kd) {
      int row = wid * 32 + 16 * m + lr;
      int ch = (4 * kd + lg) ^ (lr & 7);
      aq[m][kd] = *(const bf16x8*)&pool[row * 64 + ch * 8];
    }
  const bool anymask = (s_any[0] | s_any[1] | s_any[2] | s_any[3]) != 0;
  __syncthreads();
#pragma unroll
  for (int i = 0; i < 2; ++i) gload16(&K[ksrc[i]], &Kbuf0[ldso[i]]);
#pragma unroll
  for (int i = 0; i < 2; ++i) gload16(&V[vsrc[i]], &Vbuf0[ldso[i]]);
  __syncthreads();

  f32x4 o[2][4] = {};
  f32x4 ol[2] = {};
  const short oneb = 0x3F80;
  const bf16x8 ones8 = {oneb, oneb, oneb, oneb, oneb, oneb, oneb, oneb};
  const f32x4 zero4 = {0.f, 0.f, 0.f, 0.f};
  const int ch0 = (lg ^ (lr & 7)) * 8;
  const int ch1 = ((4 + lg) ^ (lr & 7)) * 8;
  const int sw = lr >> 1;

  for (int kb = 0; kb < 32; ++kb) {
    const int bi = kb & 1;
    const unsigned short* Kb_ = bi ? Kbuf1 : Kbuf0;
    const unsigned short* Vb_ = bi ? Vbuf1 : Vbuf0;
    unsigned short* Kn_ = bi ? Kbuf0 : Kbuf1;
    unsigned short* Vn_ = bi ? Vbuf0 : Vbuf1;
    if (kb + 1 < 32) {
      const size_t ko = (size_t)(kb + 1) * 64 * 1024;
      const size_t vo = (size_t)(kb + 1) * 64;
#pragma unroll
      for (int i = 0; i < 2; ++i) gload16(&K[ksrc[i] + ko], &Kn_[ldso[i]]);
#pragma unroll
      for (int i = 0; i < 2; ++i) gload16(&V[vsrc[i] + vo], &Vn_[ldso[i]]);
    }
    f32x4 s[2][4];
    __builtin_amdgcn_s_setprio(1);
#pragma unroll
    for (int n = 0; n < 4; ++n) {
      bf16x8 k0 = *(const bf16x8*)&Kb_[(16 * n + lr) * 64 + ch0];
      bf16x8 k1 = *(const bf16x8*)&Kb_[(16 * n + lr) * 64 + ch1];
      f32x4 t0 = __builtin_amdgcn_mfma_f32_16x16x32_bf16(k0, aq[0][0], zero4, 0, 0, 0);
      s[0][n] = __builtin_amdgcn_mfma_f32_16x16x32_bf16(k1, aq[0][1], t0, 0, 0, 0);
      f32x4 t1 = __builtin_amdgcn_mfma_f32_16x16x32_bf16(k0, aq[1][0], zero4, 0, 0, 0);
      s[1][n] = __builtin_amdgcn_mfma_f32_16x16x32_bf16(k1, aq[1][1], t1, 0, 0, 0);
    }
    __builtin_amdgcn_s_setprio(0);
    if (anymask) {
      const int* mrow = mb + kb * 64;
#pragma unroll
      for (int n = 0; n < 4; ++n) {
        int4 mv = *(const int4*)&mrow[16 * n + 4 * lg];
        int mm[4] = {mv.x, mv.y, mv.z, mv.w};
#pragma unroll
        for (int r = 0; r < 4; ++r)
          if (mm[r] == 0) { s[0][n][r] = MASKED_VAL; s[1][n][r] = MASKED_VAL; }
      }
    }
#pragma unroll
    for (int m = 0; m < 2; ++m)
#pragma unroll
      for (int n = 0; n < 4; ++n)
#pragma unroll
        for (int r = 0; r < 4; ++r) s[m][n][r] = exp2a(s[m][n][r]);
#pragma unroll
    for (int kk = 0; kk < 2; ++kk) {
      bf16x8 pf[2];
#pragma unroll
      for (int m = 0; m < 2; ++m) {
        uint4v u;
        u[0] = pk2(s[m][2 * kk][0], s[m][2 * kk][1]);
        u[1] = pk2(s[m][2 * kk][2], s[m][2 * kk][3]);
        u[2] = pk2(s[m][2 * kk + 1][0], s[m][2 * kk + 1][1]);
        u[3] = pk2(s[m][2 * kk + 1][2], s[m][2 * kk + 1][3]);
        pf[m] = __builtin_bit_cast(bf16x8, u);
      }
      __builtin_amdgcn_s_setprio(1);
      ol[0] = __builtin_amdgcn_mfma_f32_16x16x32_bf16(ones8, pf[0], ol[0], 0, 0, 0);
      ol[1] = __builtin_amdgcn_mfma_f32_16x16x32_bf16(ones8, pf[1], ol[1], 0, 0, 0);
      const int p0 = (4 * kk + (lg >> 1)) ^ sw;
      const int base0 = lr * 64 + p0 * 8 + (lg & 1) * 4;
      const int base1 = lr * 64 + (p0 ^ 2) * 8 + (lg & 1) * 4;
#pragma unroll
      for (int dn = 0; dn < 4; ++dn) {
        bf16x4 v0 = *(const bf16x4*)&Vb_[base0 + dn * 1024];
        bf16x4 v1 = *(const bf16x4*)&Vb_[base1 + dn * 1024];
        bf16x8 vb = __builtin_shufflevector(v0, v1, 0, 1, 2, 3, 4, 5, 6, 7);
#pragma unroll
        for (int m = 0; m < 2; ++m)
          o[m][dn] = __builtin_amdgcn_mfma_f32_16x16x32_bf16(vb, pf[m], o[m][dn], 0, 0, 0);
      }
      __builtin_amdgcn_s_setprio(0);
    }
    __syncthreads();
  }
#pragma unroll
  for (int m = 0; m < 2; ++m) {
    float inv = 1.f / ol[m][0];
    size_t q = rowQ0 + wid * 32 + 16 * m + lr;
#pragma unroll
    for (int dn = 0; dn < 4; ++dn) {
      ushort4v u;
#pragma unroll
      for (int r = 0; r < 4; ++r) u[r] = f2bf(o[m][dn][r] * inv);
      *(ushort4v*)&ctx[q * 1024 + hcol + 16 * dn + 4 * lg] = u;
    }
  }
}

extern "C" void kernel_launch(void* const* d_in, const int* in_sizes, int n_in,
                              void* d_out, int out_size, void* d_ws, size_t ws_size,
                              hipStream_t stream) {
  const float* srcQ = (const float*)d_in[0];
  const float* srcK = (const float*)d_in[1];
  const float* srcV = (const float*)d_in[2];
  const int*   mask = (const int*)d_in[3];
  const float* Wq = (const float*)d_in[4];
  const float* bq = (const float*)d_in[5];
  const float* Wk = (const float*)d_in[6];
  const float* bk = (const float*)d_in[7];
  const float* Wv = (const float*)d_in[8];
  const float* bv = (const float*)d_in[9];
  const float* Wo = (const float*)d_in[10];
  const float* bo = (const float*)d_in[11];
  float* out = (float*)d_out;

  char* ws = (char*)d_ws;
  unsigned short* ctx = (unsigned short*)(ws);                       // 16 MiB
  unsigned short* Qb  = (unsigned short*)(ws + (size_t)(16 << 20));
  unsigned short* Kb  = (unsigned short*)(ws + (size_t)(32 << 20));
  unsigned short* Vt  = (unsigned short*)(ws + (size_t)(48 << 20));  // V^T from V-GEMM
  unsigned short* Wt  = (unsigned short*)(ws + (size_t)(64 << 20));  // 4 x 2 MiB

  transpose_w4<<<dim3(32, 32, 4), 256, 0, stream>>>(Wq, Wk, Wv, Wo, Wt);

  gemm_qkv<<<1536, 256, 0, stream>>>(srcQ, srcK, srcV, Wt, bq, bk, bv, Qb, Kb, Vt);

  attn_kernel<<<1024, 256, 0, stream>>>(Qb, Kb, Vt, mask, ctx);

  gemm_out<<<512, 256, 0, stream>>>(ctx, Wt + 3 * (1 << 20), bo, out);
}

// Round 14
// 177.853 us; speedup vs baseline: 1.1646x; 1.0169x over previous
//
#include <hip/hip_runtime.h>

typedef short bf16x8 __attribute__((ext_vector_type(8)));
typedef short bf16x4 __attribute__((ext_vector_type(4)));
typedef float f32x4 __attribute__((ext_vector_type(4)));
typedef unsigned short ushort8 __attribute__((ext_vector_type(8)));
typedef unsigned short ushort4v __attribute__((ext_vector_type(4)));
typedef unsigned int uint4v __attribute__((ext_vector_type(4)));
typedef float float4v __attribute__((ext_vector_type(4)));

#define LOG2E 1.4426950408889634f
#define MASKED_VAL -14426.950408889634f /* -10000 * log2(e) */

__device__ __forceinline__ unsigned short f2bf(float f) {
  unsigned u = __builtin_bit_cast(unsigned, f);
  u = u + 0x7fffu + ((u >> 16) & 1u);
  return (unsigned short)(u >> 16);
}

__device__ __forceinline__ unsigned pk2(float a, float b) {
  unsigned r;
  asm("v_cvt_pk_bf16_f32 %0, %1, %2" : "=v"(r) : "v"(a), "v"(b));
  return r;
}

__device__ __forceinline__ float exp2a(float x) {
  float r;
  asm("v_exp_f32 %0, %1" : "=v"(r) : "v"(x));
  return r;
}

__device__ __forceinline__ void gload16(const void* g, void* l) {
  __builtin_amdgcn_global_load_lds(
      (const __attribute__((address_space(1))) unsigned int*)g,
      (__attribute__((address_space(3))) unsigned int*)l, 16, 0, 0);
}

// ---------------- W [K][N] fp32 -> Wt [N][K] bf16, all 4 weights fused ----------------
__global__ __launch_bounds__(256) void transpose_w4(const float* __restrict__ W0,
                                                    const float* __restrict__ W1,
                                                    const float* __restrict__ W2,
                                                    const float* __restrict__ W3,
                                                    unsigned short* __restrict__ Wt) {
  __shared__ float tile[32][33];
  const int z = blockIdx.z;
  const float* W = (z == 0) ? W0 : (z == 1) ? W1 : (z == 2) ? W2 : W3;
  unsigned short* o = Wt + (size_t)z * (1 << 20);
  int bx = blockIdx.x * 32;
  int by = blockIdx.y * 32;
  int tx = threadIdx.x & 31;
  int ty = threadIdx.x >> 5;
#pragma unroll
  for (int j = 0; j < 32; j += 8)
    tile[ty + j][tx] = W[(size_t)(by + ty + j) * 1024 + bx + tx];
  __syncthreads();
#pragma unroll
  for (int j = 0; j < 32; j += 8)
    o[(size_t)(bx + ty + j) * 1024 + by + tx] = f2bf(tile[tx][ty + j]);
}

// ---------------- Fused Q/K/V projection GEMM (128x128, 3-buffer, no-drain barriers) ----------------
__global__ __launch_bounds__(256, 3) void gemm_qkv(
    const float* __restrict__ srcQ, const float* __restrict__ srcK,
    const float* __restrict__ srcV, const unsigned short* __restrict__ Wt,
    const float* __restrict__ bq, const float* __restrict__ bk,
    const float* __restrict__ bv, unsigned short* __restrict__ Qb,
    unsigned short* __restrict__ Kb, unsigned short* __restrict__ Vt) {
  __shared__ __align__(16) unsigned short As[3][128 * 32];  // 24 KB
  __shared__ __align__(16) unsigned short Bs[3][128 * 32];  // 24 KB
  const int K = 1024, N = 1024;
  const int chunk = blockIdx.x >> 9;
  const int inner = blockIdx.x & 511;
  const int x = inner & 7, i = inner >> 3;
  const int bm = (x << 3) + (i >> 3);
  const int bn = i & 7;
  const float* Af = (chunk == 0) ? srcQ : (chunk == 1) ? srcK : srcV;
  const unsigned short* Bt = Wt + (size_t)chunk * (1 << 20);
  const float* bias = (chunk == 0) ? bq : (chunk == 1) ? bk : bv;
  const float scale = (chunk == 0) ? LOG2E : 1.0f;
  const int t = threadIdx.x;
  const int lane = t & 63, wid = t >> 6;
  const int wr = wid >> 1, wc = wid & 1;
  const int lr = lane & 15, lg = lane >> 4;
  f32x4 acc[4][4] = {};
  const size_t baseA = (size_t)(bm * 128) * K;
  const size_t baseB = (size_t)(bn * 128) * K;
  const int c0 = t, c1 = t + 256;
  const size_t a0off = baseA + (size_t)(c0 >> 2) * K + (c0 & 3) * 8;
  const size_t a1off = baseA + (size_t)(c1 >> 2) * K + (c1 & 3) * 8;
  const size_t b0off = baseB + (size_t)(c0 >> 2) * K + (c0 & 3) * 8;
  const size_t b1off = baseB + (size_t)(c1 >> 2) * K + (c1 & 3) * 8;

  unsigned short* pA0 = &As[0][0];
  unsigned short* pA1 = &As[1][0];
  unsigned short* pA2 = &As[2][0];
  unsigned short* pB0 = &Bs[0][0];
  unsigned short* pB1 = &Bs[1][0];
  unsigned short* pB2 = &Bs[2][0];
  float4v fE[4], fO[4];

  auto loadA = [&](float4v* f, int ks) {
    f[0] = *(const float4v*)&Af[a0off + ks];
    f[1] = *(const float4v*)&Af[a0off + ks + 4];
    f[2] = *(const float4v*)&Af[a1off + ks];
    f[3] = *(const float4v*)&Af[a1off + ks + 4];
  };
  auto writeA = [&](const float4v* f, unsigned short* dst) {
    uint4v w0, w1;
    w0[0] = pk2(f[0][0], f[0][1]); w0[1] = pk2(f[0][2], f[0][3]);
    w0[2] = pk2(f[1][0], f[1][1]); w0[3] = pk2(f[1][2], f[1][3]);
    w1[0] = pk2(f[2][0], f[2][1]); w1[1] = pk2(f[2][2], f[2][3]);
    w1[2] = pk2(f[3][0], f[3][1]); w1[3] = pk2(f[3][2], f[3][3]);
    *(uint4v*)&dst[c0 * 8] = w0;
    *(uint4v*)&dst[c1 * 8] = w1;
  };
  auto compute = [&]() {
    bf16x8 a[4], b[4];
#pragma unroll
    for (int m = 0; m < 4; ++m)
      a[m] = *(const bf16x8*)&pA0[(wr * 64 + 16 * m + lr) * 32 + lg * 8];
#pragma unroll
    for (int n = 0; n < 4; ++n)
      b[n] = *(const bf16x8*)&pB0[(wc * 64 + 16 * n + lr) * 32 + lg * 8];
    __builtin_amdgcn_s_setprio(1);
#pragma unroll
    for (int m = 0; m < 4; ++m)
#pragma unroll
      for (int n = 0; n < 4; ++n)
        acc[m][n] = __builtin_amdgcn_mfma_f32_16x16x32_bf16(a[m], b[n], acc[m][n], 0, 0, 0);
    __builtin_amdgcn_s_setprio(0);
  };
  auto rotate = [&]() {
    unsigned short* ta = pA0; pA0 = pA1; pA1 = pA2; pA2 = ta;
    unsigned short* tb = pB0; pB0 = pB1; pB1 = pB2; pB2 = tb;
  };

  gload16(&Bt[b0off], &pB0[c0 * 8]);
  gload16(&Bt[b1off], &pB0[c1 * 8]);
  loadA(fE, 0);
  gload16(&Bt[b0off + 32], &pB1[c0 * 8]);
  gload16(&Bt[b1off + 32], &pB1[c1 * 8]);
  loadA(fO, 32);
  writeA(fE, pA0);
  asm volatile("s_waitcnt lgkmcnt(0)" ::: "memory");
  __builtin_amdgcn_s_barrier();

  for (int it = 0; it < 16; ++it) {
    const int ks0 = 64 * it;
    if (it < 15) {
      gload16(&Bt[b0off + ks0 + 64], &pB2[c0 * 8]);
      gload16(&Bt[b1off + ks0 + 64], &pB2[c1 * 8]);
      loadA(fE, ks0 + 64);
    }
    compute();
    writeA(fO, pA1);
    asm volatile("s_waitcnt lgkmcnt(0)" ::: "memory");
    __builtin_amdgcn_sched_barrier(0);
    __builtin_amdgcn_s_barrier();
    rotate();
    if (it < 15) {
      gload16(&Bt[b0off + ks0 + 96], &pB2[c0 * 8]);
      gload16(&Bt[b1off + ks0 + 96], &pB2[c1 * 8]);
      loadA(fO, ks0 + 96);
    }
    compute();
    if (it < 15) {
      writeA(fE, pA1);
      asm volatile("s_waitcnt lgkmcnt(0)" ::: "memory");
      __builtin_amdgcn_sched_barrier(0);
      __builtin_amdgcn_s_barrier();
      rotate();
    }
  }

  const int rowb = bm * 128 + wr * 64;
  const int colb = bn * 128 + wc * 64;
  if (chunk == 2) {
    const int bidx = rowb >> 11;
    const int srow = rowb & 2047;
#pragma unroll
    for (int n = 0; n < 4; ++n) {
      int col = colb + 16 * n + lr;
      float bv_ = bias[col];
#pragma unroll
      for (int m = 0; m < 4; ++m) {
        int s0 = srow + 16 * m + 4 * lg;
        ushort4v u;
#pragma unroll
        for (int r = 0; r < 4; ++r) u[r] = f2bf(acc[m][n][r] + bv_);
        *(ushort4v*)&Vt[((size_t)(bidx * 1024 + col)) * 2048 + s0] = u;
      }
    }
  } else {
    unsigned short* C = (chunk == 0) ? Qb : Kb;
#pragma unroll
    for (int n = 0; n < 4; ++n) {
      int col = colb + 16 * n + lr;
      float bv_ = bias[col];
#pragma unroll
      for (int m = 0; m < 4; ++m) {
        int row0 = rowb + 16 * m + 4 * lg;
#pragma unroll
        for (int r = 0; r < 4; ++r)
          C[(size_t)(row0 + r) * N + col] = f2bf((acc[m][n][r] + bv_) * scale);
      }
    }
  }
}

// ---------------- Wo GEMM: out = ctx(bf16) * Wt^T + bias (fp32 out) ----------------
__global__ __launch_bounds__(256, 3) void gemm_out(const unsigned short* __restrict__ A,
                                                   const unsigned short* __restrict__ Bt,
                                                   const float* __restrict__ bias,
                                                   float* __restrict__ C) {
  __shared__ __align__(16) unsigned short As[3][128 * 32];
  __shared__ __align__(16) unsigned short Bs[3][128 * 32];
  const int K = 1024, N = 1024;
  const int x = blockIdx.x & 7, i = blockIdx.x >> 3;
  const int bm = (x << 3) + (i >> 3);
  const int bn = i & 7;
  const int t = threadIdx.x;
  const int lane = t & 63, wid = t >> 6;
  const int wr = wid >> 1, wc = wid & 1;
  const int lr = lane & 15, lg = lane >> 4;
  f32x4 acc[4][4] = {};
  const size_t baseA = (size_t)(bm * 128) * K;
  const size_t baseB = (size_t)(bn * 128) * K;
  const int c0 = t, c1 = t + 256;
  const size_t a0off = baseA + (size_t)(c0 >> 2) * K + (c0 & 3) * 8;
  const size_t a1off = baseA + (size_t)(c1 >> 2) * K + (c1 & 3) * 8;
  const size_t b0off = baseB + (size_t)(c0 >> 2) * K + (c0 & 3) * 8;
  const size_t b1off = baseB + (size_t)(c1 >> 2) * K + (c1 & 3) * 8;

  unsigned short* pA0 = &As[0][0];
  unsigned short* pA1 = &As[1][0];
  unsigned short* pA2 = &As[2][0];
  unsigned short* pB0 = &Bs[0][0];
  unsigned short* pB1 = &Bs[1][0];
  unsigned short* pB2 = &Bs[2][0];

  auto issue = [&](int ks, unsigned short* dA, unsigned short* dB) {
    gload16(&A[a0off + ks], &dA[c0 * 8]);
    gload16(&A[a1off + ks], &dA[c1 * 8]);
    gload16(&Bt[b0off + ks], &dB[c0 * 8]);
    gload16(&Bt[b1off + ks], &dB[c1 * 8]);
  };
  auto rotate = [&]() {
    unsigned short* ta = pA0; pA0 = pA1; pA1 = pA2; pA2 = ta;
    unsigned short* tb = pB0; pB0 = pB1; pB1 = pB2; pB2 = tb;
  };

  issue(0, pA0, pB0);
  issue(32, pA1, pB1);
  asm volatile("s_waitcnt vmcnt(4)" ::: "memory");
  __builtin_amdgcn_sched_barrier(0);
  __builtin_amdgcn_s_barrier();

  for (int tt = 0; tt < 32; ++tt) {
    if (tt < 30) issue(32 * tt + 64, pA2, pB2);
    bf16x8 a[4], b[4];
#pragma unroll
    for (int m = 0; m < 4; ++m)
      a[m] = *(const bf16x8*)&pA0[(wr * 64 + 16 * m + lr) * 32 + lg * 8];
#pragma unroll
    for (int n = 0; n < 4; ++n)
      b[n] = *(const bf16x8*)&pB0[(wc * 64 + 16 * n + lr) * 32 + lg * 8];
    __builtin_amdgcn_s_setprio(1);
#pragma unroll
    for (int m = 0; m < 4; ++m)
#pragma unroll
      for (int n = 0; n < 4; ++n)
        acc[m][n] = __builtin_amdgcn_mfma_f32_16x16x32_bf16(a[m], b[n], acc[m][n], 0, 0, 0);
    __builtin_amdgcn_s_setprio(0);
    if (tt < 31) {
      if (tt < 30) {
        asm volatile("s_waitcnt vmcnt(4)" ::: "memory");
      } else {
        asm volatile("s_waitcnt vmcnt(0)" ::: "memory");
      }
      __builtin_amdgcn_sched_barrier(0);
      __builtin_amdgcn_s_barrier();
      rotate();
    }
  }

  const int rowb = bm * 128 + wr * 64;
  const int colb = bn * 128 + wc * 64;
#pragma unroll
  for (int n = 0; n < 4; ++n) {
    int col = colb + 16 * n + lr;
    float bv = bias[col];
#pragma unroll
    for (int m = 0; m < 4; ++m) {
      int row0 = rowb + 16 * m + 4 * lg;
#pragma unroll
      for (int r = 0; r < 4; ++r)
        C[(size_t)(row0 + r) * N + col] = acc[m][n][r] + bv;
    }
  }
}

// ---------------- Flash attention (8 waves/block, 256 q-rows) ----------------
// grid = 512, XCD-swizzled. 8 waves x 32 q-rows, KVBLK=64, dbuf. K/V staging
// amortized over 2x q-rows; occupancy 2 blocks/CU = 16 waves/CU.
__global__ __launch_bounds__(512, 4) void attn_kernel(
    const unsigned short* __restrict__ Q, const unsigned short* __restrict__ K,
    const unsigned short* __restrict__ V, const int* __restrict__ mask,
    unsigned short* __restrict__ ctx) {
  __shared__ __align__(16) unsigned short pool[16384];  // 32 KB (Q tile 256x64 pre-loop)
  __shared__ int s_any[8];
  unsigned short* Kbuf0 = pool;
  unsigned short* Kbuf1 = pool + 4096;
  unsigned short* Vbuf0 = pool + 8192;
  unsigned short* Vbuf1 = pool + 12288;
  const int g = blockIdx.x;
  const int bid = (g & 7) * 64 + (g >> 3);  // XCD-contiguous logical id
  const int qb = bid & 7, h = (bid >> 3) & 15, b = bid >> 7;
  const int t = threadIdx.x;
  const int lane = t & 63, wid = t >> 6;
  const int lr = lane & 15, lg = lane >> 4;
  const size_t rowQ0 = (size_t)(b * 2048 + qb * 256);
  const int hcol = h * 64;
  const size_t vrow0 = (size_t)((b * 16 + h) * 64) * 2048;

  // per-thread K/V staging base (1 chunk each; 512 threads cover 64x64 tile)
  const int row_s = t >> 3, pos_s = t & 7;
  const size_t ksrc = (size_t)(b * 2048 + row_s) * 1024 + hcol + ((pos_s ^ (row_s & 7)) << 3);
  const size_t vsrc = vrow0 + (size_t)row_s * 2048 + ((pos_s ^ ((row_s >> 1) & 7)) << 3);
  const int ldso = t * 8;

  // stage Q tile [256 q][64 d] into pool (fills all 32 KB, pre-loop reuse)
#pragma unroll
  for (int i = 0; i < 4; ++i) {
    int ci = t + 512 * i;
    int row = ci >> 3, pos = ci & 7;
    gload16(&Q[(rowQ0 + row) * 1024 + hcol + ((pos ^ (row & 7)) << 3)], &pool[ci * 8]);
  }
  // block-wide mask scan (4 ints per thread)
  const int* mb = mask + b * 2048;
  int4 mv0 = *(const int4*)&mb[t * 4];
  int bad = (mv0.x == 0) | (mv0.y == 0) | (mv0.z == 0) | (mv0.w == 0);
  unsigned long long bb = __ballot(bad);
  if (lane == 0) s_any[wid] = (bb != 0ULL);
  __syncthreads();  // Q staged + s_any visible
  bf16x8 aq[2][2];
#pragma unroll
  for (int m = 0; m < 2; ++m)
#pragma unroll
    for (int kd = 0; kd < 2; ++kd) {
      int row = wid * 32 + 16 * m + lr;
      int ch = (4 * kd + lg) ^ (lr & 7);
      aq[m][kd] = *(const bf16x8*)&pool[row * 64 + ch * 8];
    }
  int anyi = 0;
#pragma unroll
  for (int w = 0; w < 8; ++w) anyi |= s_any[w];
  const bool anymask = anyi != 0;
  __syncthreads();  // all Q-frag reads done -> pool reusable
  gload16(&K[ksrc], &Kbuf0[ldso]);
  gload16(&V[vsrc], &Vbuf0[ldso]);
  __syncthreads();  // K0/V0 ready

  f32x4 o[2][4] = {};
  f32x4 ol[2] = {};
  const short oneb = 0x3F80;
  const bf16x8 ones8 = {oneb, oneb, oneb, oneb, oneb, oneb, oneb, oneb};
  const f32x4 zero4 = {0.f, 0.f, 0.f, 0.f};
  const int ch0 = (lg ^ (lr & 7)) * 8;
  const int ch1 = ((4 + lg) ^ (lr & 7)) * 8;
  const int sw = lr >> 1;

  for (int kb = 0; kb < 32; ++kb) {
    const int bi = kb & 1;
    const unsigned short* Kb_ = bi ? Kbuf1 : Kbuf0;
    const unsigned short* Vb_ = bi ? Vbuf1 : Vbuf0;
    unsigned short* Kn_ = bi ? Kbuf0 : Kbuf1;
    unsigned short* Vn_ = bi ? Vbuf0 : Vbuf1;
    if (kb + 1 < 32) {
      gload16(&K[ksrc + (size_t)(kb + 1) * 64 * 1024], &Kn_[ldso]);
      gload16(&V[vsrc + (size_t)(kb + 1) * 64], &Vn_[ldso]);
    }
    // ---- S^T = K Q^T ----
    f32x4 s[2][4];
    __builtin_amdgcn_s_setprio(1);
#pragma unroll
    for (int n = 0; n < 4; ++n) {
      bf16x8 k0 = *(const bf16x8*)&Kb_[(16 * n + lr) * 64 + ch0];
      bf16x8 k1 = *(const bf16x8*)&Kb_[(16 * n + lr) * 64 + ch1];
      f32x4 t0 = __builtin_amdgcn_mfma_f32_16x16x32_bf16(k0, aq[0][0], zero4, 0, 0, 0);
      s[0][n] = __builtin_amdgcn_mfma_f32_16x16x32_bf16(k1, aq[0][1], t0, 0, 0, 0);
      f32x4 t1 = __builtin_amdgcn_mfma_f32_16x16x32_bf16(k0, aq[1][0], zero4, 0, 0, 0);
      s[1][n] = __builtin_amdgcn_mfma_f32_16x16x32_bf16(k1, aq[1][1], t1, 0, 0, 0);
    }
    __builtin_amdgcn_s_setprio(0);
    if (anymask) {
      const int* mrow = mb + kb * 64;
#pragma unroll
      for (int n = 0; n < 4; ++n) {
        int4 mv = *(const int4*)&mrow[16 * n + 4 * lg];
        int mm[4] = {mv.x, mv.y, mv.z, mv.w};
#pragma unroll
        for (int r = 0; r < 4; ++r)
          if (mm[r] == 0) { s[0][n][r] = MASKED_VAL; s[1][n][r] = MASKED_VAL; }
      }
    }
    // ---- direct exp2 (bounded scores) ----
#pragma unroll
    for (int m = 0; m < 2; ++m)
#pragma unroll
      for (int n = 0; n < 4; ++n)
#pragma unroll
        for (int r = 0; r < 4; ++r) s[m][n][r] = exp2a(s[m][n][r]);
    // ---- O^T += V^T P^T (permuted k-slots); l via ones-MFMA ----
#pragma unroll
    for (int kk = 0; kk < 2; ++kk) {
      bf16x8 pf[2];
#pragma unroll
      for (int m = 0; m < 2; ++m) {
        uint4v u;
        u[0] = pk2(s[m][2 * kk][0], s[m][2 * kk][1]);
        u[1] = pk2(s[m][2 * kk][2], s[m][2 * kk][3]);
        u[2] = pk2(s[m][2 * kk + 1][0], s[m][2 * kk + 1][1]);
        u[3] = pk2(s[m][2 * kk + 1][2], s[m][2 * kk + 1][3]);
        pf[m] = __builtin_bit_cast(bf16x8, u);
      }
      __builtin_amdgcn_s_setprio(1);
      ol[0] = __builtin_amdgcn_mfma_f32_16x16x32_bf16(ones8, pf[0], ol[0], 0, 0, 0);
      ol[1] = __builtin_amdgcn_mfma_f32_16x16x32_bf16(ones8, pf[1], ol[1], 0, 0, 0);
      const int p0 = (4 * kk + (lg >> 1)) ^ sw;
      const int base0 = lr * 64 + p0 * 8 + (lg & 1) * 4;
      const int base1 = lr * 64 + (p0 ^ 2) * 8 + (lg & 1) * 4;
#pragma unroll
      for (int dn = 0; dn < 4; ++dn) {
        bf16x4 v0 = *(const bf16x4*)&Vb_[base0 + dn * 1024];
        bf16x4 v1 = *(const bf16x4*)&Vb_[base1 + dn * 1024];
        bf16x8 vb = __builtin_shufflevector(v0, v1, 0, 1, 2, 3, 4, 5, 6, 7);
#pragma unroll
        for (int m = 0; m < 2; ++m)
          o[m][dn] = __builtin_amdgcn_mfma_f32_16x16x32_bf16(vb, pf[m], o[m][dn], 0, 0, 0);
      }
      __builtin_amdgcn_s_setprio(0);
    }
    __syncthreads();
  }
  // ---- epilogue ----
#pragma unroll
  for (int m = 0; m < 2; ++m) {
    float inv = 1.f / ol[m][0];
    size_t q = rowQ0 + wid * 32 + 16 * m + lr;
#pragma unroll
    for (int dn = 0; dn < 4; ++dn) {
      ushort4v u;
#pragma unroll
      for (int r = 0; r < 4; ++r) u[r] = f2bf(o[m][dn][r] * inv);
      *(ushort4v*)&ctx[q * 1024 + hcol + 16 * dn + 4 * lg] = u;
    }
  }
}

extern "C" void kernel_launch(void* const* d_in, const int* in_sizes, int n_in,
                              void* d_out, int out_size, void* d_ws, size_t ws_size,
                              hipStream_t stream) {
  const float* srcQ = (const float*)d_in[0];
  const float* srcK = (const float*)d_in[1];
  const float* srcV = (const float*)d_in[2];
  const int*   mask = (const int*)d_in[3];
  const float* Wq = (const float*)d_in[4];
  const float* bq = (const float*)d_in[5];
  const float* Wk = (const float*)d_in[6];
  const float* bk = (const float*)d_in[7];
  const float* Wv = (const float*)d_in[8];
  const float* bv = (const float*)d_in[9];
  const float* Wo = (const float*)d_in[10];
  const float* bo = (const float*)d_in[11];
  float* out = (float*)d_out;

  char* ws = (char*)d_ws;
  unsigned short* ctx = (unsigned short*)(ws);                       // 16 MiB
  unsigned short* Qb  = (unsigned short*)(ws + (size_t)(16 << 20));
  unsigned short* Kb  = (unsigned short*)(ws + (size_t)(32 << 20));
  unsigned short* Vt  = (unsigned short*)(ws + (size_t)(48 << 20));  // V^T from V-GEMM
  unsigned short* Wt  = (unsigned short*)(ws + (size_t)(64 << 20));  // 4 x 2 MiB

  transpose_w4<<<dim3(32, 32, 4), 256, 0, stream>>>(Wq, Wk, Wv, Wo, Wt);

  gemm_qkv<<<1536, 256, 0, stream>>>(srcQ, srcK, srcV, Wt, bq, bk, bv, Qb, Kb, Vt);

  attn_kernel<<<512, 512, 0, stream>>>(Qb, Kb, Vt, mask, ctx);

  gemm_out<<<512, 256, 0, stream>>>(ctx, Wt + 3 * (1 << 20), bo, out);
}